// Round 1
// baseline (1483.379 us; speedup 1.0000x reference)
//
#include <hip/hip_runtime.h>
#include <math.h>

// ---------------------------------------------------------------------------
// TransformerBlock: x + attn(LN1(x)) -> x1 ; x1 + top2-MoE(LN2(x1)) ; aux loss
// Strategy notes:
//  * All big matmuls via bf16 MFMA 16x16x32 (m97-style 128x128 tile, NT layout,
//    global_load_lds width-16, BK=32, 2 barriers/K-step).
//  * Attention path (qkv, QK^T, PV, proj) uses 2-term bf16 split (hi/lo):
//    A*B ~= Ah*Bh + Al*Bh + Ah*Bl as a 3-phase K-loop -> ~1e-5 precision so the
//    router's top-2 selection matches the fp32 reference.
//  * MoE computed sparsely (only the top-2 experts per token) -- exact, since
//    gates are zero elsewhere.
// ---------------------------------------------------------------------------

typedef __bf16 bf16;
typedef __bf16 bf16x8 __attribute__((ext_vector_type(8)));
typedef float  f32x4  __attribute__((ext_vector_type(4)));

#define D_MODEL 1024
#define SEQ     1024
#define NTOK    4096
#define DFF     4096
#define NEXP    8

__device__ __forceinline__ f32x4 mfma16(bf16x8 a, bf16x8 b, f32x4 c) {
  return __builtin_amdgcn_mfma_f32_16x16x32_bf16(a, b, c, 0, 0, 0);
}

__device__ __forceinline__ void async_cp16(void* lds, const void* g) {
  __builtin_amdgcn_global_load_lds(
      (__attribute__((address_space(1))) void*)(void*)g,
      (__attribute__((address_space(3))) void*)lds, 16, 0, 0);
}

// ---------------------------------------------------------------------------
// Shared MFMA GEMM core: C[128x128] tile, A [M][K] rows via per-lane offsets,
// B stored transposed [N][K]. SPLIT => 3 phases (Ah*Bh, Al*Bh, Ah*Bl).
// ---------------------------------------------------------------------------
template<bool SPLIT>
__device__ __forceinline__ void gemm_core(
    const bf16* __restrict__ Ahi, const bf16* __restrict__ Alo,
    const bf16* __restrict__ Bhi, const bf16* __restrict__ Blo,
    long aOff0, long aOff1, long bOff0, long bOff1,
    int K, bf16* As, bf16* Bs, f32x4 acc[4][4])
{
  const int tid  = threadIdx.x;
  const int lane = tid & 63, w = tid >> 6;
  const int fr   = lane & 15, quad = lane >> 4;
  const int wm   = w >> 1,    wn   = w & 1;
  bf16* AsD0 = As + (w * 16) * 32;
  bf16* AsD1 = As + (64 + w * 16) * 32;
  bf16* BsD0 = Bs + (w * 16) * 32;
  bf16* BsD1 = Bs + (64 + w * 16) * 32;
  const int nph = SPLIT ? 3 : 1;
  for (int ph = 0; ph < nph; ++ph) {
    const bf16* Ap = (ph == 1) ? Alo : Ahi;
    const bf16* Bp = (ph == 2) ? Blo : Bhi;
    for (int k0 = 0; k0 < K; k0 += 32) {
      async_cp16(AsD0, Ap + aOff0 + k0);
      async_cp16(AsD1, Ap + aOff1 + k0);
      async_cp16(BsD0, Bp + bOff0 + k0);
      async_cp16(BsD1, Bp + bOff1 + k0);
      __syncthreads();
      bf16x8 af[4], bfv[4];
#pragma unroll
      for (int mi = 0; mi < 4; ++mi)
        af[mi] = *(const bf16x8*)&As[(wm * 64 + mi * 16 + fr) * 32 + quad * 8];
#pragma unroll
      for (int ni = 0; ni < 4; ++ni)
        bfv[ni] = *(const bf16x8*)&Bs[(wn * 64 + ni * 16 + fr) * 32 + quad * 8];
#pragma unroll
      for (int mi = 0; mi < 4; ++mi)
#pragma unroll
        for (int ni = 0; ni < 4; ++ni)
          acc[mi][ni] = mfma16(af[mi], bfv[ni], acc[mi][ni]);
      __syncthreads();
    }
  }
}

// ---------------------------------------------------------------------------
// Weight transpose + fp32->bf16(hi[,lo]) cast: in [Z][K][N] -> out [Z][N][K]
// ---------------------------------------------------------------------------
__global__ void k_transpose_cast(const float* __restrict__ in,
                                 bf16* __restrict__ oh, bf16* __restrict__ ol,
                                 int K, int N)
{
  const long zo = (long)blockIdx.z * K * N;
  __shared__ float tile[32][33];
  const int tx = threadIdx.x & 31, ty = threadIdx.x >> 5;
  const int r0 = blockIdx.y * 32, c0 = blockIdx.x * 32;
#pragma unroll
  for (int j = 0; j < 4; ++j)
    tile[ty + 8 * j][tx] = in[zo + (long)(r0 + ty + 8 * j) * N + (c0 + tx)];
  __syncthreads();
#pragma unroll
  for (int j = 0; j < 4; ++j) {
    float v = tile[tx][ty + 8 * j];
    long  o = zo + (long)(c0 + ty + 8 * j) * K + (r0 + tx);
    bf16 hh = (bf16)v;
    oh[o] = hh;
    if (ol) ol[o] = (bf16)(v - (float)hh);
  }
}

// ---------------------------------------------------------------------------
// LayerNorm: one block per token, writes bf16 hi (and lo if non-null)
// ---------------------------------------------------------------------------
__global__ __launch_bounds__(256) void k_layernorm(
    const float* __restrict__ x, const float* __restrict__ g,
    const float* __restrict__ b, bf16* __restrict__ oh, bf16* __restrict__ ol)
{
  const int tok = blockIdx.x, tid = threadIdx.x;
  const float4 v = ((const float4*)(x + (long)tok * D_MODEL))[tid];
  float s  = v.x + v.y + v.z + v.w;
  float s2 = v.x * v.x + v.y * v.y + v.z * v.z + v.w * v.w;
#pragma unroll
  for (int off = 1; off < 64; off <<= 1) {
    s  += __shfl_xor(s, off);
    s2 += __shfl_xor(s2, off);
  }
  __shared__ float red[8];
  if ((tid & 63) == 0) { red[tid >> 6] = s; red[4 + (tid >> 6)] = s2; }
  __syncthreads();
  s  = red[0] + red[1] + red[2] + red[3];
  s2 = red[4] + red[5] + red[6] + red[7];
  const float mu   = s * (1.0f / D_MODEL);
  const float var  = s2 * (1.0f / D_MODEL) - mu * mu;
  const float rstd = 1.0f / sqrtf(var + 1e-5f);
  const float4 gg = ((const float4*)g)[tid];
  const float4 bb = ((const float4*)b)[tid];
  float o0 = (v.x - mu) * rstd * gg.x + bb.x;
  float o1 = (v.y - mu) * rstd * gg.y + bb.y;
  float o2 = (v.z - mu) * rstd * gg.z + bb.z;
  float o3 = (v.w - mu) * rstd * gg.w + bb.w;
  const long base = (long)tok * D_MODEL + tid * 4;
  bf16 h0 = (bf16)o0, h1 = (bf16)o1, h2 = (bf16)o2, h3 = (bf16)o3;
  oh[base + 0] = h0; oh[base + 1] = h1; oh[base + 2] = h2; oh[base + 3] = h3;
  if (ol) {
    ol[base + 0] = (bf16)(o0 - (float)h0);
    ol[base + 1] = (bf16)(o1 - (float)h1);
    ol[base + 2] = (bf16)(o2 - (float)h2);
    ol[base + 3] = (bf16)(o3 - (float)h3);
  }
}

// ---------------------------------------------------------------------------
// QKV GEMM (split): ln1[4096][1024] @ wqkvT -> qkv fp32 [4096][3072]
// ---------------------------------------------------------------------------
__global__ __launch_bounds__(256, 2) void k_gemm_qkv(
    const bf16* __restrict__ Ah, const bf16* __restrict__ Al,
    const bf16* __restrict__ Bh, const bf16* __restrict__ Bl,
    float* __restrict__ out)
{
  __shared__ __align__(16) bf16 As[128 * 32];
  __shared__ __align__(16) bf16 Bs[128 * 32];
  const int tid = threadIdx.x, lane = tid & 63, w = tid >> 6;
  const int fr = lane & 15, quad = lane >> 4;
  const int wm = w >> 1, wn = w & 1;
  const int m0 = blockIdx.y * 128, n0 = blockIdx.x * 128;
  const int lrow = w * 16 + (lane >> 2), colk = (lane & 3) * 8;
  long aOff0 = (long)(m0 + lrow) * D_MODEL + colk;
  long aOff1 = aOff0 + 64L * D_MODEL;
  long bOff0 = (long)(n0 + lrow) * D_MODEL + colk;
  long bOff1 = bOff0 + 64L * D_MODEL;
  f32x4 acc[4][4];
  f32x4 zv = {0.f, 0.f, 0.f, 0.f};
#pragma unroll
  for (int i = 0; i < 4; ++i)
#pragma unroll
    for (int j = 0; j < 4; ++j) acc[i][j] = zv;
  gemm_core<true>(Ah, Al, Bh, Bl, aOff0, aOff1, bOff0, bOff1, D_MODEL, As, Bs, acc);
#pragma unroll
  for (int mi = 0; mi < 4; ++mi)
#pragma unroll
    for (int ni = 0; ni < 4; ++ni) {
      const int col = n0 + wn * 64 + ni * 16 + fr;
#pragma unroll
      for (int r = 0; r < 4; ++r) {
        const int row = m0 + wm * 64 + mi * 16 + quad * 4 + r;
        out[(long)row * 3072 + col] = acc[mi][ni][r];
      }
    }
}

// ---------------------------------------------------------------------------
// RoPE + layout: qkv fp32 [tok][3072] -> q,k (rotated), v ; split hi/lo,
// head-major [bh][t][64]
// ---------------------------------------------------------------------------
__global__ __launch_bounds__(256) void k_rope(
    const float* __restrict__ qkv,
    bf16* __restrict__ qh, bf16* __restrict__ ql,
    bf16* __restrict__ kh, bf16* __restrict__ kl,
    bf16* __restrict__ vh, bf16* __restrict__ vl)
{
  const int tok = blockIdx.x;
  const int t = tok & (SEQ - 1), bb = tok >> 10;
  const int tid = threadIdx.x;
  const float ft = (float)t;
  for (int it = tid; it < 512; it += 256) {
    const int hh = it >> 5, i = it & 31;
    const float inv = powf(10000.0f, -(float)i * (1.0f / 32.0f));
    const float ang = ft * inv;
    float sn, cs;
    sincosf(ang, &sn, &cs);
    const long src = (long)tok * 3072 + hh * 64 + i;
    const float q0 = qkv[src], q1 = qkv[src + 32];
    const float k0 = qkv[src + 1024], k1 = qkv[src + 1024 + 32];
    const float qo0 = q0 * cs - q1 * sn, qo1 = q1 * cs + q0 * sn;
    const float ko0 = k0 * cs - k1 * sn, ko1 = k1 * cs + k0 * sn;
    const long dst = ((long)(bb * 16 + hh) * SEQ + t) * 64 + i;
    bf16 x;
    x = (bf16)qo0; qh[dst] = x;      ql[dst] = (bf16)(qo0 - (float)x);
    x = (bf16)qo1; qh[dst + 32] = x; ql[dst + 32] = (bf16)(qo1 - (float)x);
    x = (bf16)ko0; kh[dst] = x;      kl[dst] = (bf16)(ko0 - (float)x);
    x = (bf16)ko1; kh[dst + 32] = x; kl[dst + 32] = (bf16)(ko1 - (float)x);
  }
  for (int it = tid; it < 1024; it += 256) {
    const int hh = it >> 6, d = it & 63;
    const float vv = qkv[(long)tok * 3072 + 2048 + it];
    const long dst = ((long)(bb * 16 + hh) * SEQ + t) * 64 + d;
    bf16 x = (bf16)vv;
    vh[dst] = x; vl[dst] = (bf16)(vv - (float)x);
  }
}

// ---------------------------------------------------------------------------
// Flash attention (causal), split-precision QK^T and PV. Block = 64 q-rows.
// ---------------------------------------------------------------------------
__global__ __launch_bounds__(256, 2) void k_flash(
    const bf16* __restrict__ qh, const bf16* __restrict__ ql,
    const bf16* __restrict__ kh, const bf16* __restrict__ kl,
    const bf16* __restrict__ vh, const bf16* __restrict__ vl,
    bf16* __restrict__ oh, bf16* __restrict__ ol)
{
  const int qt = blockIdx.x, bhid = blockIdx.y;
  const int tid = threadIdx.x, lane = tid & 63, w = tid >> 6;
  const int fr = lane & 15, quad = lane >> 4;
  __shared__ __align__(16) bf16 Qh[64 * 64], Ql[64 * 64];
  __shared__ __align__(16) bf16 Kh[64 * 64], Kl[64 * 64];
  __shared__ __align__(16) bf16 Vh[64 * 64], Vl[64 * 64];
  __shared__ __align__(16) bf16 Ps[4][16 * 64], Pl[4][16 * 64];

  const long qbase = ((long)bhid * SEQ + qt * 64) * 64;
  for (int c = tid; c < 512; c += 256) {
    const int row = c >> 3, c8 = (c & 7) << 3;
    *(uint4*)&Qh[row * 64 + c8] = *(const uint4*)&qh[qbase + row * 64 + c8];
    *(uint4*)&Ql[row * 64 + c8] = *(const uint4*)&ql[qbase + row * 64 + c8];
  }
  __syncthreads();
  bf16x8 aQh[2], aQl[2];
#pragma unroll
  for (int kk = 0; kk < 2; ++kk) {
    aQh[kk] = *(const bf16x8*)&Qh[(w * 16 + fr) * 64 + kk * 32 + quad * 8];
    aQl[kk] = *(const bf16x8*)&Ql[(w * 16 + fr) * 64 + kk * 32 + quad * 8];
  }
  f32x4 o[4];
  f32x4 zv = {0.f, 0.f, 0.f, 0.f};
#pragma unroll
  for (int ct = 0; ct < 4; ++ct) o[ct] = zv;
  float m_r[4], l_r[4];
#pragma unroll
  for (int r = 0; r < 4; ++r) { m_r[r] = -1e30f; l_r[r] = 0.f; }

  for (int kt = 0; kt <= qt; ++kt) {
    __syncthreads();
    const long kbase = ((long)bhid * SEQ + kt * 64) * 64;
    for (int c = tid; c < 512; c += 256) {
      const int row = c >> 3, c8 = (c & 7) << 3;
      *(uint4*)&Kh[row * 64 + c8] = *(const uint4*)&kh[kbase + row * 64 + c8];
      *(uint4*)&Kl[row * 64 + c8] = *(const uint4*)&kl[kbase + row * 64 + c8];
      uint4 uh = *(const uint4*)&vh[kbase + row * 64 + c8];
      uint4 ul = *(const uint4*)&vl[kbase + row * 64 + c8];
      const bf16* vph = (const bf16*)&uh;
      const bf16* vpl = (const bf16*)&ul;
#pragma unroll
      for (int j = 0; j < 8; ++j) {   // transpose V into [d][key]
        Vh[(c8 + j) * 64 + row] = vph[j];
        Vl[(c8 + j) * 64 + row] = vpl[j];
      }
    }
    __syncthreads();

    f32x4 s[4];
#pragma unroll
    for (int nt = 0; nt < 4; ++nt) s[nt] = zv;
#pragma unroll
    for (int nt = 0; nt < 4; ++nt)
#pragma unroll
      for (int kk = 0; kk < 2; ++kk) {
        bf16x8 bh8 = *(const bf16x8*)&Kh[(nt * 16 + fr) * 64 + kk * 32 + quad * 8];
        bf16x8 bl8 = *(const bf16x8*)&Kl[(nt * 16 + fr) * 64 + kk * 32 + quad * 8];
        s[nt] = mfma16(aQh[kk], bh8, s[nt]);
        s[nt] = mfma16(aQl[kk], bh8, s[nt]);
        s[nt] = mfma16(aQh[kk], bl8, s[nt]);
      }
    const int qloc = w * 16 + quad * 4;  // + r
#pragma unroll
    for (int nt = 0; nt < 4; ++nt)
#pragma unroll
      for (int r = 0; r < 4; ++r) {
        float sv = s[nt][r] * 0.125f;
        if (kt == qt && (nt * 16 + fr) > (qloc + r)) sv = -1e30f;
        s[nt][r] = sv;
      }
    float al4[4];
#pragma unroll
    for (int r = 0; r < 4; ++r) {
      float m = fmaxf(fmaxf(s[0][r], s[1][r]), fmaxf(s[2][r], s[3][r]));
#pragma unroll
      for (int off = 1; off < 16; off <<= 1) m = fmaxf(m, __shfl_xor(m, off));
      const float mn = fmaxf(m_r[r], m);
      al4[r] = expf(m_r[r] - mn);
      m_r[r] = mn;
    }
    float pmat[4][4], ls4[4];
#pragma unroll
    for (int r = 0; r < 4; ++r) ls4[r] = 0.f;
#pragma unroll
    for (int nt = 0; nt < 4; ++nt)
#pragma unroll
      for (int r = 0; r < 4; ++r) {
        const float p = expf(s[nt][r] - m_r[r]);
        pmat[nt][r] = p;
        ls4[r] += p;
      }
#pragma unroll
    for (int r = 0; r < 4; ++r) {
      float l = ls4[r];
#pragma unroll
      for (int off = 1; off < 16; off <<= 1) l += __shfl_xor(l, off);
      l_r[r] = l_r[r] * al4[r] + l;
      o[0][r] *= al4[r]; o[1][r] *= al4[r]; o[2][r] *= al4[r]; o[3][r] *= al4[r];
    }
#pragma unroll
    for (int nt = 0; nt < 4; ++nt)
#pragma unroll
      for (int r = 0; r < 4; ++r) {
        const float p = pmat[nt][r];
        bf16 hh2 = (bf16)p;
        Ps[w][(quad * 4 + r) * 64 + nt * 16 + fr] = hh2;
        Pl[w][(quad * 4 + r) * 64 + nt * 16 + fr] = (bf16)(p - (float)hh2);
      }
    __syncthreads();
#pragma unroll
    for (int kk = 0; kk < 2; ++kk) {
      bf16x8 aPh = *(const bf16x8*)&Ps[w][fr * 64 + kk * 32 + quad * 8];
      bf16x8 aPl = *(const bf16x8*)&Pl[w][fr * 64 + kk * 32 + quad * 8];
#pragma unroll
      for (int ct = 0; ct < 4; ++ct) {
        bf16x8 bVh = *(const bf16x8*)&Vh[(ct * 16 + fr) * 64 + kk * 32 + quad * 8];
        bf16x8 bVl = *(const bf16x8*)&Vl[(ct * 16 + fr) * 64 + kk * 32 + quad * 8];
        o[ct] = mfma16(aPh, bVh, o[ct]);
        o[ct] = mfma16(aPl, bVh, o[ct]);
        o[ct] = mfma16(aPh, bVl, o[ct]);
      }
    }
  }
  const int b_ = bhid >> 4, h_ = bhid & 15;
#pragma unroll
  for (int ct = 0; ct < 4; ++ct)
#pragma unroll
    for (int r = 0; r < 4; ++r) {
      const int tokn = b_ * SEQ + qt * 64 + w * 16 + quad * 4 + r;
      const int col = h_ * 64 + ct * 16 + fr;
      const float val = o[ct][r] / l_r[r];
      bf16 hh3 = (bf16)val;
      oh[(long)tokn * D_MODEL + col] = hh3;
      ol[(long)tokn * D_MODEL + col] = (bf16)(val - (float)hh3);
    }
}

// ---------------------------------------------------------------------------
// Proj GEMM (split) + bias + residual -> d_out fp32 (= x1)
// ---------------------------------------------------------------------------
__global__ __launch_bounds__(256, 2) void k_gemm_proj(
    const bf16* __restrict__ Ah, const bf16* __restrict__ Al,
    const bf16* __restrict__ Bh, const bf16* __restrict__ Bl,
    const float* __restrict__ bproj, const float* __restrict__ xin,
    float* __restrict__ out)
{
  __shared__ __align__(16) bf16 As[128 * 32];
  __shared__ __align__(16) bf16 Bs[128 * 32];
  const int tid = threadIdx.x, lane = tid & 63, w = tid >> 6;
  const int fr = lane & 15, quad = lane >> 4;
  const int wm = w >> 1, wn = w & 1;
  const int m0 = blockIdx.y * 128, n0 = blockIdx.x * 128;
  const int lrow = w * 16 + (lane >> 2), colk = (lane & 3) * 8;
  long aOff0 = (long)(m0 + lrow) * D_MODEL + colk;
  long aOff1 = aOff0 + 64L * D_MODEL;
  long bOff0 = (long)(n0 + lrow) * D_MODEL + colk;
  long bOff1 = bOff0 + 64L * D_MODEL;
  f32x4 acc[4][4];
  f32x4 zv = {0.f, 0.f, 0.f, 0.f};
#pragma unroll
  for (int i = 0; i < 4; ++i)
#pragma unroll
    for (int j = 0; j < 4; ++j) acc[i][j] = zv;
  gemm_core<true>(Ah, Al, Bh, Bl, aOff0, aOff1, bOff0, bOff1, D_MODEL, As, Bs, acc);
#pragma unroll
  for (int mi = 0; mi < 4; ++mi)
#pragma unroll
    for (int ni = 0; ni < 4; ++ni) {
      const int col = n0 + wn * 64 + ni * 16 + fr;
#pragma unroll
      for (int r = 0; r < 4; ++r) {
        const int row = m0 + wm * 64 + mi * 16 + quad * 4 + r;
        out[(long)row * D_MODEL + col] =
            acc[mi][ni][r] + bproj[col] + xin[(long)row * D_MODEL + col];
      }
    }
}

// ---------------------------------------------------------------------------
// Router: own fp32 LN of x1, fp32 logits, softmax, strict top-2, expert lists
// ---------------------------------------------------------------------------
__global__ __launch_bounds__(256) void k_router(
    const float* __restrict__ x1, const float* __restrict__ g,
    const float* __restrict__ b, const float* __restrict__ wr,
    int* __restrict__ ecnt, float* __restrict__ psum,
    int* __restrict__ perm, float* __restrict__ gatew)
{
  const int tok = blockIdx.x, tid = threadIdx.x;
  const float4 v = ((const float4*)(x1 + (long)tok * D_MODEL))[tid];
  float s  = v.x + v.y + v.z + v.w;
  float s2 = v.x * v.x + v.y * v.y + v.z * v.z + v.w * v.w;
#pragma unroll
  for (int off = 1; off < 64; off <<= 1) {
    s  += __shfl_xor(s, off);
    s2 += __shfl_xor(s2, off);
  }
  __shared__ float red[8];
  __shared__ float lr[4][8];
  if ((tid & 63) == 0) { red[tid >> 6] = s; red[4 + (tid >> 6)] = s2; }
  __syncthreads();
  s  = red[0] + red[1] + red[2] + red[3];
  s2 = red[4] + red[5] + red[6] + red[7];
  const float mu   = s * (1.0f / D_MODEL);
  const float var  = s2 * (1.0f / D_MODEL) - mu * mu;
  const float rstd = 1.0f / sqrtf(var + 1e-5f);
  const float4 gg = ((const float4*)g)[tid];
  const float4 bb = ((const float4*)b)[tid];
  float n4[4];
  n4[0] = (v.x - mu) * rstd * gg.x + bb.x;
  n4[1] = (v.y - mu) * rstd * gg.y + bb.y;
  n4[2] = (v.z - mu) * rstd * gg.z + bb.z;
  n4[3] = (v.w - mu) * rstd * gg.w + bb.w;
  float part[8];
#pragma unroll
  for (int e = 0; e < 8; ++e) part[e] = 0.f;
  const float* wrow = wr + (long)tid * 4 * 8;
#pragma unroll
  for (int c = 0; c < 4; ++c)
#pragma unroll
    for (int e = 0; e < 8; ++e) part[e] += n4[c] * wrow[c * 8 + e];
#pragma unroll
  for (int off = 1; off < 64; off <<= 1)
#pragma unroll
    for (int e = 0; e < 8; ++e) part[e] += __shfl_xor(part[e], off);
  if ((tid & 63) == 0)
#pragma unroll
    for (int e = 0; e < 8; ++e) lr[tid >> 6][e] = part[e];
  __syncthreads();
  if (tid == 0) {
    float lg[8];
#pragma unroll
    for (int e = 0; e < 8; ++e) lg[e] = lr[0][e] + lr[1][e] + lr[2][e] + lr[3][e];
    float mx = lg[0];
#pragma unroll
    for (int e = 1; e < 8; ++e) mx = fmaxf(mx, lg[e]);
    float pe[8], ssum = 0.f;
#pragma unroll
    for (int e = 0; e < 8; ++e) { pe[e] = expf(lg[e] - mx); ssum += pe[e]; }
    const float inv = 1.0f / ssum;
    int i1 = -1, i2 = -1;
    float v1 = -1.f, v2 = -1.f;
#pragma unroll
    for (int e = 0; e < 8; ++e) {
      const float p = pe[e] * inv;
      pe[e] = p;
      atomicAdd(&psum[e], p);
      if (p > v1)      { v2 = v1; i2 = i1; v1 = p; i1 = e; }
      else if (p > v2) { v2 = p; i2 = e; }
    }
    const float wsum = v1 + v2;
    const float g1 = v1 / wsum, g2 = v2 / wsum;
    int p1 = atomicAdd(&ecnt[i1], 1);
    perm[i1 * NTOK + p1] = tok; gatew[i1 * NTOK + p1] = g1;
    int p2 = atomicAdd(&ecnt[i2], 1);
    perm[i2 * NTOK + p2] = tok; gatew[i2 * NTOK + p2] = g2;
  }
}

__global__ void k_finalize(const int* __restrict__ ecnt,
                           const float* __restrict__ psum,
                           int* __restrict__ eoff, float* __restrict__ aux_out)
{
  if (threadIdx.x == 0 && blockIdx.x == 0) {
    int off = 0;
    float aux = 0.f;
    for (int e = 0; e < 8; ++e) {
      eoff[e] = off;
      off += (ecnt[e] + 127) & ~127;
      aux += ((float)ecnt[e] * (1.0f / (NTOK * 2.0f))) * (psum[e] * (1.0f / NTOK));
    }
    aux_out[0] = 8.0f * aux;
  }
}

// ---------------------------------------------------------------------------
// FFN1: gathered ln2 rows @ w1T[e] + b1 -> exact GELU -> h (bf16)
// ---------------------------------------------------------------------------
__global__ __launch_bounds__(256, 2) void k_gemm_ffn1(
    const bf16* __restrict__ A, const bf16* __restrict__ w1t,
    const float* __restrict__ b1, const int* __restrict__ ecnt,
    const int* __restrict__ eoff, const int* __restrict__ perm,
    bf16* __restrict__ h)
{
  const int e = blockIdx.y >> 5, mt = blockIdx.y & 31;
  const int cnt = ecnt[e];
  if (mt * 128 >= cnt) return;
  __shared__ __align__(16) bf16 As[128 * 32];
  __shared__ __align__(16) bf16 Bs[128 * 32];
  const int tid = threadIdx.x, lane = tid & 63, w = tid >> 6;
  const int fr = lane & 15, quad = lane >> 4;
  const int wm = w >> 1, wn = w & 1;
  const int n0 = blockIdx.x * 128;
  const int lrow = w * 16 + (lane >> 2), colk = (lane & 3) * 8;
  int i0 = mt * 128 + lrow;
  int i1 = i0 + 64;
  i0 = min(i0, cnt - 1);
  i1 = min(i1, cnt - 1);
  const int* pe = perm + e * NTOK;
  long aOff0 = (long)pe[i0] * D_MODEL + colk;
  long aOff1 = (long)pe[i1] * D_MODEL + colk;
  const bf16* B = w1t + (long)e * DFF * D_MODEL;
  long bOff0 = (long)(n0 + lrow) * D_MODEL + colk;
  long bOff1 = bOff0 + 64L * D_MODEL;
  f32x4 acc[4][4];
  f32x4 zv = {0.f, 0.f, 0.f, 0.f};
#pragma unroll
  for (int i = 0; i < 4; ++i)
#pragma unroll
    for (int j = 0; j < 4; ++j) acc[i][j] = zv;
  gemm_core<false>(A, A, B, B, aOff0, aOff1, bOff0, bOff1, D_MODEL, As, Bs, acc);
  const int hbase = eoff[e] + mt * 128;
#pragma unroll
  for (int mi = 0; mi < 4; ++mi)
#pragma unroll
    for (int ni = 0; ni < 4; ++ni) {
      const int col = n0 + wn * 64 + ni * 16 + fr;
#pragma unroll
      for (int r = 0; r < 4; ++r) {
        const int irow = wm * 64 + mi * 16 + quad * 4 + r;
        const float vv = acc[mi][ni][r] + b1[e * DFF + col];
        const float ge = 0.5f * vv * (1.0f + erff(vv * 0.70710678118654752f));
        h[(long)(hbase + irow) * DFF + col] = (bf16)ge;
      }
    }
}

// ---------------------------------------------------------------------------
// FFN2: h rows @ w2T[e] + b2, gated atomic scatter-add into d_out
// ---------------------------------------------------------------------------
__global__ __launch_bounds__(256, 2) void k_gemm_ffn2(
    const bf16* __restrict__ hbuf, const bf16* __restrict__ w2t,
    const float* __restrict__ b2, const int* __restrict__ ecnt,
    const int* __restrict__ eoff, const int* __restrict__ perm,
    const float* __restrict__ gatew, float* __restrict__ out)
{
  const int e = blockIdx.y >> 5, mt = blockIdx.y & 31;
  const int cnt = ecnt[e];
  if (mt * 128 >= cnt) return;
  __shared__ __align__(16) bf16 As[128 * 32];
  __shared__ __align__(16) bf16 Bs[128 * 32];
  const int tid = threadIdx.x, lane = tid & 63, w = tid >> 6;
  const int fr = lane & 15, quad = lane >> 4;
  const int wm = w >> 1, wn = w & 1;
  const int n0 = blockIdx.x * 128;
  const int lrow = w * 16 + (lane >> 2), colk = (lane & 3) * 8;
  const bf16* A = hbuf + (long)(eoff[e] + mt * 128) * DFF;
  long aOff0 = (long)lrow * DFF + colk;
  long aOff1 = aOff0 + 64L * DFF;
  const bf16* B = w2t + (long)e * D_MODEL * DFF;
  long bOff0 = (long)(n0 + lrow) * DFF + colk;
  long bOff1 = bOff0 + 64L * DFF;
  f32x4 acc[4][4];
  f32x4 zv = {0.f, 0.f, 0.f, 0.f};
#pragma unroll
  for (int i = 0; i < 4; ++i)
#pragma unroll
    for (int j = 0; j < 4; ++j) acc[i][j] = zv;
  gemm_core<false>(A, A, B, B, aOff0, aOff1, bOff0, bOff1, DFF, As, Bs, acc);
#pragma unroll
  for (int mi = 0; mi < 4; ++mi)
#pragma unroll
    for (int ni = 0; ni < 4; ++ni) {
      const int col = n0 + wn * 64 + ni * 16 + fr;
#pragma unroll
      for (int r = 0; r < 4; ++r) {
        const int irow = wm * 64 + mi * 16 + quad * 4 + r;
        const int gi = mt * 128 + irow;
        if (gi < cnt) {
          const int tok = perm[e * NTOK + gi];
          const float gw = gatew[e * NTOK + gi];
          const float vv = acc[mi][ni][r] + b2[e * D_MODEL + col];
          atomicAdd(&out[(long)tok * D_MODEL + col], vv * gw);
        }
      }
    }
}

// ---------------------------------------------------------------------------
extern "C" void kernel_launch(void* const* d_in, const int* in_sizes, int n_in,
                              void* d_out, int out_size, void* d_ws, size_t ws_size,
                              hipStream_t stream) {
  const float* x     = (const float*)d_in[0];
  // d_in[1] = mask (causal structure reproduced in-kernel)
  const float* ln1g  = (const float*)d_in[2];
  const float* ln1b  = (const float*)d_in[3];
  const float* wqkv  = (const float*)d_in[4];
  const float* wproj = (const float*)d_in[5];
  const float* bproj = (const float*)d_in[6];
  const float* ln2g  = (const float*)d_in[7];
  const float* ln2b  = (const float*)d_in[8];
  const float* wrout = (const float*)d_in[9];
  const float* w1    = (const float*)d_in[10];
  const float* b1    = (const float*)d_in[11];
  const float* w2    = (const float*)d_in[12];
  const float* b2    = (const float*)d_in[13];
  float* out = (float*)d_out;

  char* p = (char*)d_ws;
  auto alloc = [&](size_t n) { char* r = p; p += (n + 255) & ~(size_t)255; return r; };

  bf16* wqkvT_h = (bf16*)alloc(3072L * 1024 * 2);
  bf16* wqkvT_l = (bf16*)alloc(3072L * 1024 * 2);
  bf16* wprojT_h = (bf16*)alloc(1024L * 1024 * 2);
  bf16* wprojT_l = (bf16*)alloc(1024L * 1024 * 2);
  bf16* w1T = (bf16*)alloc(8L * 4096 * 1024 * 2);
  bf16* w2T = (bf16*)alloc(8L * 1024 * 4096 * 2);
  bf16* ln_h = (bf16*)alloc(4096L * 1024 * 2);  // ln1 then reused for ln2
  bf16* ln_l = (bf16*)alloc(4096L * 1024 * 2);
  bf16* attn_h = (bf16*)alloc(4096L * 1024 * 2);
  bf16* attn_l = (bf16*)alloc(4096L * 1024 * 2);
  int*   perm  = (int*)alloc(8L * 4096 * 4);
  float* gatew = (float*)alloc(8L * 4096 * 4);
  char*  ctrl  = alloc(256);                 // ecnt[8] | psum[8] | eoff[8]
  int*   ecnt  = (int*)ctrl;
  float* psum  = (float*)(ctrl + 64);
  int*   eoff  = (int*)(ctrl + 128);
  // big overlay region: [qkv fp32 48MB | rope hi/lo bufs 48MB] then h (73MB)
  char* big = alloc(100663296);
  float* qkvf = (float*)big;                           // 4096*3072*4
  bf16* qh = (bf16*)(big + 50331648);
  bf16* ql = qh + 4194304;
  bf16* kh = ql + 4194304;
  bf16* kl = kh + 4194304;
  bf16* vh = kl + 4194304;
  bf16* vl = vh + 4194304;
  bf16* hbuf = (bf16*)big;                             // 9216*4096*2, after attn

  dim3 blk(256);

  // 1) weight transpose + cast
  k_transpose_cast<<<dim3(3072 / 32, 1024 / 32, 1), blk, 0, stream>>>(wqkv, wqkvT_h, wqkvT_l, 1024, 3072);
  k_transpose_cast<<<dim3(1024 / 32, 1024 / 32, 1), blk, 0, stream>>>(wproj, wprojT_h, wprojT_l, 1024, 1024);
  k_transpose_cast<<<dim3(4096 / 32, 1024 / 32, 8), blk, 0, stream>>>(w1, w1T, nullptr, 1024, 4096);
  k_transpose_cast<<<dim3(1024 / 32, 4096 / 32, 8), blk, 0, stream>>>(w2, w2T, nullptr, 4096, 1024);
  hipMemsetAsync(ctrl, 0, 256, stream);

  // 2) attention path (split precision)
  k_layernorm<<<4096, blk, 0, stream>>>(x, ln1g, ln1b, ln_h, ln_l);
  k_gemm_qkv<<<dim3(24, 32), blk, 0, stream>>>(ln_h, ln_l, wqkvT_h, wqkvT_l, qkvf);
  k_rope<<<4096, blk, 0, stream>>>(qkvf, qh, ql, kh, kl, vh, vl);
  k_flash<<<dim3(16, 64), blk, 0, stream>>>(qh, ql, kh, kl, vh, vl, attn_h, attn_l);
  k_gemm_proj<<<dim3(8, 32), blk, 0, stream>>>(attn_h, attn_l, wprojT_h, wprojT_l, bproj, x, out);

  // 3) MoE
  k_layernorm<<<4096, blk, 0, stream>>>(out, ln2g, ln2b, ln_h, nullptr);
  k_router<<<4096, blk, 0, stream>>>(out, ln2g, ln2b, wrout, ecnt, psum, perm, gatew);
  k_finalize<<<1, 64, 0, stream>>>(ecnt, psum, eoff, out + 4194304);
  k_gemm_ffn1<<<dim3(32, 256), blk, 0, stream>>>(ln_h, w1T, b1, ecnt, eoff, perm, hbuf);
  k_gemm_ffn2<<<dim3(8, 256), blk, 0, stream>>>(hbuf, w2T, b2, ecnt, eoff, perm, gatew, out);
}

// Round 2
// 1106.831 us; speedup vs baseline: 1.3402x; 1.3402x over previous
//
#include <hip/hip_runtime.h>
#include <math.h>

// ---------------------------------------------------------------------------
// TransformerBlock: x + attn(LN1(x)) -> x1 ; x1 + top2-MoE(LN2(x1)) ; aux loss
// R2: router atomics de-contended (424us -> ~10us predicted).
//  * k_router now writes per-token top2 + probs (no global atomics).
//  * k_scatter builds expert lists with per-block LDS histograms + 8 global
//    atomics per block (was: 8192 serialized atomics on 8 addresses).
//  * k_finalize reduces the probs buffer for psum + aux.
// ---------------------------------------------------------------------------

typedef __bf16 bf16;
typedef __bf16 bf16x8 __attribute__((ext_vector_type(8)));
typedef float  f32x4  __attribute__((ext_vector_type(4)));

#define D_MODEL 1024
#define SEQ     1024
#define NTOK    4096
#define DFF     4096
#define NEXP    8

__device__ __forceinline__ f32x4 mfma16(bf16x8 a, bf16x8 b, f32x4 c) {
  return __builtin_amdgcn_mfma_f32_16x16x32_bf16(a, b, c, 0, 0, 0);
}

__device__ __forceinline__ void async_cp16(void* lds, const void* g) {
  __builtin_amdgcn_global_load_lds(
      (__attribute__((address_space(1))) void*)(void*)g,
      (__attribute__((address_space(3))) void*)lds, 16, 0, 0);
}

// ---------------------------------------------------------------------------
// Shared MFMA GEMM core: C[128x128] tile, A [M][K] rows via per-lane offsets,
// B stored transposed [N][K]. SPLIT => 3 phases (Ah*Bh, Al*Bh, Ah*Bl).
// ---------------------------------------------------------------------------
template<bool SPLIT>
__device__ __forceinline__ void gemm_core(
    const bf16* __restrict__ Ahi, const bf16* __restrict__ Alo,
    const bf16* __restrict__ Bhi, const bf16* __restrict__ Blo,
    long aOff0, long aOff1, long bOff0, long bOff1,
    int K, bf16* As, bf16* Bs, f32x4 acc[4][4])
{
  const int tid  = threadIdx.x;
  const int lane = tid & 63, w = tid >> 6;
  const int fr   = lane & 15, quad = lane >> 4;
  const int wm   = w >> 1,    wn   = w & 1;
  bf16* AsD0 = As + (w * 16) * 32;
  bf16* AsD1 = As + (64 + w * 16) * 32;
  bf16* BsD0 = Bs + (w * 16) * 32;
  bf16* BsD1 = Bs + (64 + w * 16) * 32;
  const int nph = SPLIT ? 3 : 1;
  for (int ph = 0; ph < nph; ++ph) {
    const bf16* Ap = (ph == 1) ? Alo : Ahi;
    const bf16* Bp = (ph == 2) ? Blo : Bhi;
    for (int k0 = 0; k0 < K; k0 += 32) {
      async_cp16(AsD0, Ap + aOff0 + k0);
      async_cp16(AsD1, Ap + aOff1 + k0);
      async_cp16(BsD0, Bp + bOff0 + k0);
      async_cp16(BsD1, Bp + bOff1 + k0);
      __syncthreads();
      bf16x8 af[4], bfv[4];
#pragma unroll
      for (int mi = 0; mi < 4; ++mi)
        af[mi] = *(const bf16x8*)&As[(wm * 64 + mi * 16 + fr) * 32 + quad * 8];
#pragma unroll
      for (int ni = 0; ni < 4; ++ni)
        bfv[ni] = *(const bf16x8*)&Bs[(wn * 64 + ni * 16 + fr) * 32 + quad * 8];
#pragma unroll
      for (int mi = 0; mi < 4; ++mi)
#pragma unroll
        for (int ni = 0; ni < 4; ++ni)
          acc[mi][ni] = mfma16(af[mi], bfv[ni], acc[mi][ni]);
      __syncthreads();
    }
  }
}

// ---------------------------------------------------------------------------
// Weight transpose + fp32->bf16(hi[,lo]) cast: in [Z][K][N] -> out [Z][N][K]
// ---------------------------------------------------------------------------
__global__ void k_transpose_cast(const float* __restrict__ in,
                                 bf16* __restrict__ oh, bf16* __restrict__ ol,
                                 int K, int N)
{
  const long zo = (long)blockIdx.z * K * N;
  __shared__ float tile[32][33];
  const int tx = threadIdx.x & 31, ty = threadIdx.x >> 5;
  const int r0 = blockIdx.y * 32, c0 = blockIdx.x * 32;
#pragma unroll
  for (int j = 0; j < 4; ++j)
    tile[ty + 8 * j][tx] = in[zo + (long)(r0 + ty + 8 * j) * N + (c0 + tx)];
  __syncthreads();
#pragma unroll
  for (int j = 0; j < 4; ++j) {
    float v = tile[tx][ty + 8 * j];
    long  o = zo + (long)(c0 + ty + 8 * j) * K + (r0 + tx);
    bf16 hh = (bf16)v;
    oh[o] = hh;
    if (ol) ol[o] = (bf16)(v - (float)hh);
  }
}

// ---------------------------------------------------------------------------
// LayerNorm: one block per token, writes bf16 hi (and lo if non-null)
// ---------------------------------------------------------------------------
__global__ __launch_bounds__(256) void k_layernorm(
    const float* __restrict__ x, const float* __restrict__ g,
    const float* __restrict__ b, bf16* __restrict__ oh, bf16* __restrict__ ol)
{
  const int tok = blockIdx.x, tid = threadIdx.x;
  const float4 v = ((const float4*)(x + (long)tok * D_MODEL))[tid];
  float s  = v.x + v.y + v.z + v.w;
  float s2 = v.x * v.x + v.y * v.y + v.z * v.z + v.w * v.w;
#pragma unroll
  for (int off = 1; off < 64; off <<= 1) {
    s  += __shfl_xor(s, off);
    s2 += __shfl_xor(s2, off);
  }
  __shared__ float red[8];
  if ((tid & 63) == 0) { red[tid >> 6] = s; red[4 + (tid >> 6)] = s2; }
  __syncthreads();
  s  = red[0] + red[1] + red[2] + red[3];
  s2 = red[4] + red[5] + red[6] + red[7];
  const float mu   = s * (1.0f / D_MODEL);
  const float var  = s2 * (1.0f / D_MODEL) - mu * mu;
  const float rstd = 1.0f / sqrtf(var + 1e-5f);
  const float4 gg = ((const float4*)g)[tid];
  const float4 bb = ((const float4*)b)[tid];
  float o0 = (v.x - mu) * rstd * gg.x + bb.x;
  float o1 = (v.y - mu) * rstd * gg.y + bb.y;
  float o2 = (v.z - mu) * rstd * gg.z + bb.z;
  float o3 = (v.w - mu) * rstd * gg.w + bb.w;
  const long base = (long)tok * D_MODEL + tid * 4;
  bf16 h0 = (bf16)o0, h1 = (bf16)o1, h2 = (bf16)o2, h3 = (bf16)o3;
  oh[base + 0] = h0; oh[base + 1] = h1; oh[base + 2] = h2; oh[base + 3] = h3;
  if (ol) {
    ol[base + 0] = (bf16)(o0 - (float)h0);
    ol[base + 1] = (bf16)(o1 - (float)h1);
    ol[base + 2] = (bf16)(o2 - (float)h2);
    ol[base + 3] = (bf16)(o3 - (float)h3);
  }
}

// ---------------------------------------------------------------------------
// QKV GEMM (split): ln1[4096][1024] @ wqkvT -> qkv fp32 [4096][3072]
// ---------------------------------------------------------------------------
__global__ __launch_bounds__(256, 2) void k_gemm_qkv(
    const bf16* __restrict__ Ah, const bf16* __restrict__ Al,
    const bf16* __restrict__ Bh, const bf16* __restrict__ Bl,
    float* __restrict__ out)
{
  __shared__ __align__(16) bf16 As[128 * 32];
  __shared__ __align__(16) bf16 Bs[128 * 32];
  const int tid = threadIdx.x, lane = tid & 63, w = tid >> 6;
  const int fr = lane & 15, quad = lane >> 4;
  const int wm = w >> 1, wn = w & 1;
  const int m0 = blockIdx.y * 128, n0 = blockIdx.x * 128;
  const int lrow = w * 16 + (lane >> 2), colk = (lane & 3) * 8;
  long aOff0 = (long)(m0 + lrow) * D_MODEL + colk;
  long aOff1 = aOff0 + 64L * D_MODEL;
  long bOff0 = (long)(n0 + lrow) * D_MODEL + colk;
  long bOff1 = bOff0 + 64L * D_MODEL;
  f32x4 acc[4][4];
  f32x4 zv = {0.f, 0.f, 0.f, 0.f};
#pragma unroll
  for (int i = 0; i < 4; ++i)
#pragma unroll
    for (int j = 0; j < 4; ++j) acc[i][j] = zv;
  gemm_core<true>(Ah, Al, Bh, Bl, aOff0, aOff1, bOff0, bOff1, D_MODEL, As, Bs, acc);
#pragma unroll
  for (int mi = 0; mi < 4; ++mi)
#pragma unroll
    for (int ni = 0; ni < 4; ++ni) {
      const int col = n0 + wn * 64 + ni * 16 + fr;
#pragma unroll
      for (int r = 0; r < 4; ++r) {
        const int row = m0 + wm * 64 + mi * 16 + quad * 4 + r;
        out[(long)row * 3072 + col] = acc[mi][ni][r];
      }
    }
}

// ---------------------------------------------------------------------------
// RoPE + layout: qkv fp32 [tok][3072] -> q,k (rotated), v ; split hi/lo,
// head-major [bh][t][64]
// ---------------------------------------------------------------------------
__global__ __launch_bounds__(256) void k_rope(
    const float* __restrict__ qkv,
    bf16* __restrict__ qh, bf16* __restrict__ ql,
    bf16* __restrict__ kh, bf16* __restrict__ kl,
    bf16* __restrict__ vh, bf16* __restrict__ vl)
{
  const int tok = blockIdx.x;
  const int t = tok & (SEQ - 1), bb = tok >> 10;
  const int tid = threadIdx.x;
  const float ft = (float)t;
  for (int it = tid; it < 512; it += 256) {
    const int hh = it >> 5, i = it & 31;
    const float inv = powf(10000.0f, -(float)i * (1.0f / 32.0f));
    const float ang = ft * inv;
    float sn, cs;
    sincosf(ang, &sn, &cs);
    const long src = (long)tok * 3072 + hh * 64 + i;
    const float q0 = qkv[src], q1 = qkv[src + 32];
    const float k0 = qkv[src + 1024], k1 = qkv[src + 1024 + 32];
    const float qo0 = q0 * cs - q1 * sn, qo1 = q1 * cs + q0 * sn;
    const float ko0 = k0 * cs - k1 * sn, ko1 = k1 * cs + k0 * sn;
    const long dst = ((long)(bb * 16 + hh) * SEQ + t) * 64 + i;
    bf16 x;
    x = (bf16)qo0; qh[dst] = x;      ql[dst] = (bf16)(qo0 - (float)x);
    x = (bf16)qo1; qh[dst + 32] = x; ql[dst + 32] = (bf16)(qo1 - (float)x);
    x = (bf16)ko0; kh[dst] = x;      kl[dst] = (bf16)(ko0 - (float)x);
    x = (bf16)ko1; kh[dst + 32] = x; kl[dst + 32] = (bf16)(ko1 - (float)x);
  }
  for (int it = tid; it < 1024; it += 256) {
    const int hh = it >> 6, d = it & 63;
    const float vv = qkv[(long)tok * 3072 + 2048 + it];
    const long dst = ((long)(bb * 16 + hh) * SEQ + t) * 64 + d;
    bf16 x = (bf16)vv;
    vh[dst] = x; vl[dst] = (bf16)(vv - (float)x);
  }
}

// ---------------------------------------------------------------------------
// Flash attention (causal), split-precision QK^T and PV. Block = 64 q-rows.
// ---------------------------------------------------------------------------
__global__ __launch_bounds__(256, 2) void k_flash(
    const bf16* __restrict__ qh, const bf16* __restrict__ ql,
    const bf16* __restrict__ kh, const bf16* __restrict__ kl,
    const bf16* __restrict__ vh, const bf16* __restrict__ vl,
    bf16* __restrict__ oh, bf16* __restrict__ ol)
{
  const int qt = blockIdx.x, bhid = blockIdx.y;
  const int tid = threadIdx.x, lane = tid & 63, w = tid >> 6;
  const int fr = lane & 15, quad = lane >> 4;
  __shared__ __align__(16) bf16 Qh[64 * 64], Ql[64 * 64];
  __shared__ __align__(16) bf16 Kh[64 * 64], Kl[64 * 64];
  __shared__ __align__(16) bf16 Vh[64 * 64], Vl[64 * 64];
  __shared__ __align__(16) bf16 Ps[4][16 * 64], Pl[4][16 * 64];

  const long qbase = ((long)bhid * SEQ + qt * 64) * 64;
  for (int c = tid; c < 512; c += 256) {
    const int row = c >> 3, c8 = (c & 7) << 3;
    *(uint4*)&Qh[row * 64 + c8] = *(const uint4*)&qh[qbase + row * 64 + c8];
    *(uint4*)&Ql[row * 64 + c8] = *(const uint4*)&ql[qbase + row * 64 + c8];
  }
  __syncthreads();
  bf16x8 aQh[2], aQl[2];
#pragma unroll
  for (int kk = 0; kk < 2; ++kk) {
    aQh[kk] = *(const bf16x8*)&Qh[(w * 16 + fr) * 64 + kk * 32 + quad * 8];
    aQl[kk] = *(const bf16x8*)&Ql[(w * 16 + fr) * 64 + kk * 32 + quad * 8];
  }
  f32x4 o[4];
  f32x4 zv = {0.f, 0.f, 0.f, 0.f};
#pragma unroll
  for (int ct = 0; ct < 4; ++ct) o[ct] = zv;
  float m_r[4], l_r[4];
#pragma unroll
  for (int r = 0; r < 4; ++r) { m_r[r] = -1e30f; l_r[r] = 0.f; }

  for (int kt = 0; kt <= qt; ++kt) {
    __syncthreads();
    const long kbase = ((long)bhid * SEQ + kt * 64) * 64;
    for (int c = tid; c < 512; c += 256) {
      const int row = c >> 3, c8 = (c & 7) << 3;
      *(uint4*)&Kh[row * 64 + c8] = *(const uint4*)&kh[kbase + row * 64 + c8];
      *(uint4*)&Kl[row * 64 + c8] = *(const uint4*)&kl[kbase + row * 64 + c8];
      uint4 uh = *(const uint4*)&vh[kbase + row * 64 + c8];
      uint4 ul = *(const uint4*)&vl[kbase + row * 64 + c8];
      const bf16* vph = (const bf16*)&uh;
      const bf16* vpl = (const bf16*)&ul;
#pragma unroll
      for (int j = 0; j < 8; ++j) {   // transpose V into [d][key]
        Vh[(c8 + j) * 64 + row] = vph[j];
        Vl[(c8 + j) * 64 + row] = vpl[j];
      }
    }
    __syncthreads();

    f32x4 s[4];
#pragma unroll
    for (int nt = 0; nt < 4; ++nt) s[nt] = zv;
#pragma unroll
    for (int nt = 0; nt < 4; ++nt)
#pragma unroll
      for (int kk = 0; kk < 2; ++kk) {
        bf16x8 bh8 = *(const bf16x8*)&Kh[(nt * 16 + fr) * 64 + kk * 32 + quad * 8];
        bf16x8 bl8 = *(const bf16x8*)&Kl[(nt * 16 + fr) * 64 + kk * 32 + quad * 8];
        s[nt] = mfma16(aQh[kk], bh8, s[nt]);
        s[nt] = mfma16(aQl[kk], bh8, s[nt]);
        s[nt] = mfma16(aQh[kk], bl8, s[nt]);
      }
    const int qloc = w * 16 + quad * 4;  // + r
#pragma unroll
    for (int nt = 0; nt < 4; ++nt)
#pragma unroll
      for (int r = 0; r < 4; ++r) {
        float sv = s[nt][r] * 0.125f;
        if (kt == qt && (nt * 16 + fr) > (qloc + r)) sv = -1e30f;
        s[nt][r] = sv;
      }
    float al4[4];
#pragma unroll
    for (int r = 0; r < 4; ++r) {
      float m = fmaxf(fmaxf(s[0][r], s[1][r]), fmaxf(s[2][r], s[3][r]));
#pragma unroll
      for (int off = 1; off < 16; off <<= 1) m = fmaxf(m, __shfl_xor(m, off));
      const float mn = fmaxf(m_r[r], m);
      al4[r] = expf(m_r[r] - mn);
      m_r[r] = mn;
    }
    float pmat[4][4], ls4[4];
#pragma unroll
    for (int r = 0; r < 4; ++r) ls4[r] = 0.f;
#pragma unroll
    for (int nt = 0; nt < 4; ++nt)
#pragma unroll
      for (int r = 0; r < 4; ++r) {
        const float p = expf(s[nt][r] - m_r[r]);
        pmat[nt][r] = p;
        ls4[r] += p;
      }
#pragma unroll
    for (int r = 0; r < 4; ++r) {
      float l = ls4[r];
#pragma unroll
      for (int off = 1; off < 16; off <<= 1) l += __shfl_xor(l, off);
      l_r[r] = l_r[r] * al4[r] + l;
      o[0][r] *= al4[r]; o[1][r] *= al4[r]; o[2][r] *= al4[r]; o[3][r] *= al4[r];
    }
#pragma unroll
    for (int nt = 0; nt < 4; ++nt)
#pragma unroll
      for (int r = 0; r < 4; ++r) {
        const float p = pmat[nt][r];
        bf16 hh2 = (bf16)p;
        Ps[w][(quad * 4 + r) * 64 + nt * 16 + fr] = hh2;
        Pl[w][(quad * 4 + r) * 64 + nt * 16 + fr] = (bf16)(p - (float)hh2);
      }
    __syncthreads();
#pragma unroll
    for (int kk = 0; kk < 2; ++kk) {
      bf16x8 aPh = *(const bf16x8*)&Ps[w][fr * 64 + kk * 32 + quad * 8];
      bf16x8 aPl = *(const bf16x8*)&Pl[w][fr * 64 + kk * 32 + quad * 8];
#pragma unroll
      for (int ct = 0; ct < 4; ++ct) {
        bf16x8 bVh = *(const bf16x8*)&Vh[(ct * 16 + fr) * 64 + kk * 32 + quad * 8];
        bf16x8 bVl = *(const bf16x8*)&Vl[(ct * 16 + fr) * 64 + kk * 32 + quad * 8];
        o[ct] = mfma16(aPh, bVh, o[ct]);
        o[ct] = mfma16(aPl, bVh, o[ct]);
        o[ct] = mfma16(aPh, bVl, o[ct]);
      }
    }
  }
  const int b_ = bhid >> 4, h_ = bhid & 15;
#pragma unroll
  for (int ct = 0; ct < 4; ++ct)
#pragma unroll
    for (int r = 0; r < 4; ++r) {
      const int tokn = b_ * SEQ + qt * 64 + w * 16 + quad * 4 + r;
      const int col = h_ * 64 + ct * 16 + fr;
      const float val = o[ct][r] / l_r[r];
      bf16 hh3 = (bf16)val;
      oh[(long)tokn * D_MODEL + col] = hh3;
      ol[(long)tokn * D_MODEL + col] = (bf16)(val - (float)hh3);
    }
}

// ---------------------------------------------------------------------------
// Proj GEMM (split) + bias + residual -> d_out fp32 (= x1)
// ---------------------------------------------------------------------------
__global__ __launch_bounds__(256, 2) void k_gemm_proj(
    const bf16* __restrict__ Ah, const bf16* __restrict__ Al,
    const bf16* __restrict__ Bh, const bf16* __restrict__ Bl,
    const float* __restrict__ bproj, const float* __restrict__ xin,
    float* __restrict__ out)
{
  __shared__ __align__(16) bf16 As[128 * 32];
  __shared__ __align__(16) bf16 Bs[128 * 32];
  const int tid = threadIdx.x, lane = tid & 63, w = tid >> 6;
  const int fr = lane & 15, quad = lane >> 4;
  const int wm = w >> 1, wn = w & 1;
  const int m0 = blockIdx.y * 128, n0 = blockIdx.x * 128;
  const int lrow = w * 16 + (lane >> 2), colk = (lane & 3) * 8;
  long aOff0 = (long)(m0 + lrow) * D_MODEL + colk;
  long aOff1 = aOff0 + 64L * D_MODEL;
  long bOff0 = (long)(n0 + lrow) * D_MODEL + colk;
  long bOff1 = bOff0 + 64L * D_MODEL;
  f32x4 acc[4][4];
  f32x4 zv = {0.f, 0.f, 0.f, 0.f};
#pragma unroll
  for (int i = 0; i < 4; ++i)
#pragma unroll
    for (int j = 0; j < 4; ++j) acc[i][j] = zv;
  gemm_core<true>(Ah, Al, Bh, Bl, aOff0, aOff1, bOff0, bOff1, D_MODEL, As, Bs, acc);
#pragma unroll
  for (int mi = 0; mi < 4; ++mi)
#pragma unroll
    for (int ni = 0; ni < 4; ++ni) {
      const int col = n0 + wn * 64 + ni * 16 + fr;
#pragma unroll
      for (int r = 0; r < 4; ++r) {
        const int row = m0 + wm * 64 + mi * 16 + quad * 4 + r;
        out[(long)row * D_MODEL + col] =
            acc[mi][ni][r] + bproj[col] + xin[(long)row * D_MODEL + col];
      }
    }
}

// ---------------------------------------------------------------------------
// Router: own fp32 LN of x1, fp32 logits, softmax, strict top-2.
// NO global atomics: writes topi/topg per token + probs to pbuf.
// ---------------------------------------------------------------------------
__global__ __launch_bounds__(256) void k_router(
    const float* __restrict__ x1, const float* __restrict__ g,
    const float* __restrict__ b, const float* __restrict__ wr,
    int2* __restrict__ topi, float2* __restrict__ topg,
    float* __restrict__ pbuf)
{
  const int tok = blockIdx.x, tid = threadIdx.x;
  const float4 v = ((const float4*)(x1 + (long)tok * D_MODEL))[tid];
  float s  = v.x + v.y + v.z + v.w;
  float s2 = v.x * v.x + v.y * v.y + v.z * v.z + v.w * v.w;
#pragma unroll
  for (int off = 1; off < 64; off <<= 1) {
    s  += __shfl_xor(s, off);
    s2 += __shfl_xor(s2, off);
  }
  __shared__ float red[8];
  __shared__ float lr[4][8];
  if ((tid & 63) == 0) { red[tid >> 6] = s; red[4 + (tid >> 6)] = s2; }
  __syncthreads();
  s  = red[0] + red[1] + red[2] + red[3];
  s2 = red[4] + red[5] + red[6] + red[7];
  const float mu   = s * (1.0f / D_MODEL);
  const float var  = s2 * (1.0f / D_MODEL) - mu * mu;
  const float rstd = 1.0f / sqrtf(var + 1e-5f);
  const float4 gg = ((const float4*)g)[tid];
  const float4 bb = ((const float4*)b)[tid];
  float n4[4];
  n4[0] = (v.x - mu) * rstd * gg.x + bb.x;
  n4[1] = (v.y - mu) * rstd * gg.y + bb.y;
  n4[2] = (v.z - mu) * rstd * gg.z + bb.z;
  n4[3] = (v.w - mu) * rstd * gg.w + bb.w;
  float part[8];
#pragma unroll
  for (int e = 0; e < 8; ++e) part[e] = 0.f;
  const float* wrow = wr + (long)tid * 4 * 8;
#pragma unroll
  for (int c = 0; c < 4; ++c)
#pragma unroll
    for (int e = 0; e < 8; ++e) part[e] += n4[c] * wrow[c * 8 + e];
#pragma unroll
  for (int off = 1; off < 64; off <<= 1)
#pragma unroll
    for (int e = 0; e < 8; ++e) part[e] += __shfl_xor(part[e], off);
  if ((tid & 63) == 0)
#pragma unroll
    for (int e = 0; e < 8; ++e) lr[tid >> 6][e] = part[e];
  __syncthreads();
  if (tid == 0) {
    float lg[8];
#pragma unroll
    for (int e = 0; e < 8; ++e) lg[e] = lr[0][e] + lr[1][e] + lr[2][e] + lr[3][e];
    float mx = lg[0];
#pragma unroll
    for (int e = 1; e < 8; ++e) mx = fmaxf(mx, lg[e]);
    float pe[8], ssum = 0.f;
#pragma unroll
    for (int e = 0; e < 8; ++e) { pe[e] = expf(lg[e] - mx); ssum += pe[e]; }
    const float inv = 1.0f / ssum;
    int i1 = -1, i2 = -1;
    float v1 = -1.f, v2 = -1.f;
#pragma unroll
    for (int e = 0; e < 8; ++e) {
      const float p = pe[e] * inv;
      pbuf[(long)tok * 8 + e] = p;
      if (p > v1)      { v2 = v1; i2 = i1; v1 = p; i1 = e; }
      else if (p > v2) { v2 = p; i2 = e; }
    }
    const float wsum = v1 + v2;
    topi[tok] = make_int2(i1, i2);
    topg[tok] = make_float2(v1 / wsum, v2 / wsum);
  }
}

// ---------------------------------------------------------------------------
// Scatter: build per-expert token lists. 16 blocks x 256 tokens; LDS
// histogram + local ranks, then 8 global atomics per block to claim ranges.
// ---------------------------------------------------------------------------
__global__ __launch_bounds__(256) void k_scatter(
    const int2* __restrict__ topi, const float2* __restrict__ topg,
    int* __restrict__ ecnt, int* __restrict__ perm, float* __restrict__ gatew)
{
  __shared__ int hcnt[NEXP];
  __shared__ int hbase[NEXP];
  const int tid = threadIdx.x;
  const int tok = blockIdx.x * 256 + tid;
  if (tid < NEXP) hcnt[tid] = 0;
  __syncthreads();
  const int2 ti = topi[tok];
  const float2 tg = topg[tok];
  const int r1 = atomicAdd(&hcnt[ti.x], 1);
  const int r2 = atomicAdd(&hcnt[ti.y], 1);
  __syncthreads();
  if (tid < NEXP) hbase[tid] = atomicAdd(&ecnt[tid], hcnt[tid]);
  __syncthreads();
  const int p1 = hbase[ti.x] + r1;
  perm[ti.x * NTOK + p1] = tok; gatew[ti.x * NTOK + p1] = tg.x;
  const int p2 = hbase[ti.y] + r2;
  perm[ti.y * NTOK + p2] = tok; gatew[ti.y * NTOK + p2] = tg.y;
}

// ---------------------------------------------------------------------------
// Finalize: reduce pbuf -> psum, compute eoff + aux loss.
// ---------------------------------------------------------------------------
__global__ __launch_bounds__(256) void k_finalize(
    const int* __restrict__ ecnt, const float* __restrict__ pbuf,
    int* __restrict__ eoff, float* __restrict__ aux_out)
{
  __shared__ float partial[256];
  const int tid = threadIdx.x;
  const int e = tid & 7, i0 = tid >> 3;
  float sum = 0.f;
  for (int i = i0; i < NTOK; i += 32) sum += pbuf[(long)i * 8 + e];
  partial[tid] = sum;
  __syncthreads();
  if (tid < 8) {
    float ps = 0.f;
#pragma unroll
    for (int j = 0; j < 32; ++j) ps += partial[j * 8 + tid];
    partial[tid] = ps;   // psum[e]
  }
  __syncthreads();
  if (tid == 0) {
    int off = 0;
    float aux = 0.f;
    for (int e2 = 0; e2 < 8; ++e2) {
      eoff[e2] = off;
      off += (ecnt[e2] + 127) & ~127;
      aux += ((float)ecnt[e2] * (1.0f / (NTOK * 2.0f))) * (partial[e2] * (1.0f / NTOK));
    }
    aux_out[0] = 8.0f * aux;
  }
}

// ---------------------------------------------------------------------------
// FFN1: gathered ln2 rows @ w1T[e] + b1 -> exact GELU -> h (bf16)
// ---------------------------------------------------------------------------
__global__ __launch_bounds__(256, 2) void k_gemm_ffn1(
    const bf16* __restrict__ A, const bf16* __restrict__ w1t,
    const float* __restrict__ b1, const int* __restrict__ ecnt,
    const int* __restrict__ eoff, const int* __restrict__ perm,
    bf16* __restrict__ h)
{
  const int e = blockIdx.y >> 5, mt = blockIdx.y & 31;
  const int cnt = ecnt[e];
  if (mt * 128 >= cnt) return;
  __shared__ __align__(16) bf16 As[128 * 32];
  __shared__ __align__(16) bf16 Bs[128 * 32];
  const int tid = threadIdx.x, lane = tid & 63, w = tid >> 6;
  const int fr = lane & 15, quad = lane >> 4;
  const int wm = w >> 1, wn = w & 1;
  const int n0 = blockIdx.x * 128;
  const int lrow = w * 16 + (lane >> 2), colk = (lane & 3) * 8;
  int i0 = mt * 128 + lrow;
  int i1 = i0 + 64;
  i0 = min(i0, cnt - 1);
  i1 = min(i1, cnt - 1);
  const int* pe = perm + e * NTOK;
  long aOff0 = (long)pe[i0] * D_MODEL + colk;
  long aOff1 = (long)pe[i1] * D_MODEL + colk;
  const bf16* B = w1t + (long)e * DFF * D_MODEL;
  long bOff0 = (long)(n0 + lrow) * D_MODEL + colk;
  long bOff1 = bOff0 + 64L * D_MODEL;
  f32x4 acc[4][4];
  f32x4 zv = {0.f, 0.f, 0.f, 0.f};
#pragma unroll
  for (int i = 0; i < 4; ++i)
#pragma unroll
    for (int j = 0; j < 4; ++j) acc[i][j] = zv;
  gemm_core<false>(A, A, B, B, aOff0, aOff1, bOff0, bOff1, D_MODEL, As, Bs, acc);
  const int hbase = eoff[e] + mt * 128;
#pragma unroll
  for (int mi = 0; mi < 4; ++mi)
#pragma unroll
    for (int ni = 0; ni < 4; ++ni) {
      const int col = n0 + wn * 64 + ni * 16 + fr;
#pragma unroll
      for (int r = 0; r < 4; ++r) {
        const int irow = wm * 64 + mi * 16 + quad * 4 + r;
        const float vv = acc[mi][ni][r] + b1[e * DFF + col];
        const float ge = 0.5f * vv * (1.0f + erff(vv * 0.70710678118654752f));
        h[(long)(hbase + irow) * DFF + col] = (bf16)ge;
      }
    }
}

// ---------------------------------------------------------------------------
// FFN2: h rows @ w2T[e] + b2, gated atomic scatter-add into d_out
// ---------------------------------------------------------------------------
__global__ __launch_bounds__(256, 2) void k_gemm_ffn2(
    const bf16* __restrict__ hbuf, const bf16* __restrict__ w2t,
    const float* __restrict__ b2, const int* __restrict__ ecnt,
    const int* __restrict__ eoff, const int* __restrict__ perm,
    const float* __restrict__ gatew, float* __restrict__ out)
{
  const int e = blockIdx.y >> 5, mt = blockIdx.y & 31;
  const int cnt = ecnt[e];
  if (mt * 128 >= cnt) return;
  __shared__ __align__(16) bf16 As[128 * 32];
  __shared__ __align__(16) bf16 Bs[128 * 32];
  const int tid = threadIdx.x, lane = tid & 63, w = tid >> 6;
  const int fr = lane & 15, quad = lane >> 4;
  const int wm = w >> 1, wn = w & 1;
  const int n0 = blockIdx.x * 128;
  const int lrow = w * 16 + (lane >> 2), colk = (lane & 3) * 8;
  const bf16* A = hbuf + (long)(eoff[e] + mt * 128) * DFF;
  long aOff0 = (long)lrow * DFF + colk;
  long aOff1 = aOff0 + 64L * DFF;
  const bf16* B = w2t + (long)e * D_MODEL * DFF;
  long bOff0 = (long)(n0 + lrow) * DFF + colk;
  long bOff1 = bOff0 + 64L * DFF;
  f32x4 acc[4][4];
  f32x4 zv = {0.f, 0.f, 0.f, 0.f};
#pragma unroll
  for (int i = 0; i < 4; ++i)
#pragma unroll
    for (int j = 0; j < 4; ++j) acc[i][j] = zv;
  gemm_core<false>(A, A, B, B, aOff0, aOff1, bOff0, bOff1, DFF, As, Bs, acc);
#pragma unroll
  for (int mi = 0; mi < 4; ++mi)
#pragma unroll
    for (int ni = 0; ni < 4; ++ni) {
      const int col = n0 + wn * 64 + ni * 16 + fr;
#pragma unroll
      for (int r = 0; r < 4; ++r) {
        const int irow = wm * 64 + mi * 16 + quad * 4 + r;
        const int gi = mt * 128 + irow;
        if (gi < cnt) {
          const int tok = perm[e * NTOK + gi];
          const float gw = gatew[e * NTOK + gi];
          const float vv = acc[mi][ni][r] + b2[e * D_MODEL + col];
          atomicAdd(&out[(long)tok * D_MODEL + col], vv * gw);
        }
      }
    }
}

// ---------------------------------------------------------------------------
extern "C" void kernel_launch(void* const* d_in, const int* in_sizes, int n_in,
                              void* d_out, int out_size, void* d_ws, size_t ws_size,
                              hipStream_t stream) {
  const float* x     = (const float*)d_in[0];
  // d_in[1] = mask (causal structure reproduced in-kernel)
  const float* ln1g  = (const float*)d_in[2];
  const float* ln1b  = (const float*)d_in[3];
  const float* wqkv  = (const float*)d_in[4];
  const float* wproj = (const float*)d_in[5];
  const float* bproj = (const float*)d_in[6];
  const float* ln2g  = (const float*)d_in[7];
  const float* ln2b  = (const float*)d_in[8];
  const float* wrout = (const float*)d_in[9];
  const float* w1    = (const float*)d_in[10];
  const float* b1    = (const float*)d_in[11];
  const float* w2    = (const float*)d_in[12];
  const float* b2    = (const float*)d_in[13];
  float* out = (float*)d_out;

  char* p = (char*)d_ws;
  auto alloc = [&](size_t n) { char* r = p; p += (n + 255) & ~(size_t)255; return r; };

  bf16* wqkvT_h = (bf16*)alloc(3072L * 1024 * 2);
  bf16* wqkvT_l = (bf16*)alloc(3072L * 1024 * 2);
  bf16* wprojT_h = (bf16*)alloc(1024L * 1024 * 2);
  bf16* wprojT_l = (bf16*)alloc(1024L * 1024 * 2);
  bf16* w1T = (bf16*)alloc(8L * 4096 * 1024 * 2);
  bf16* w2T = (bf16*)alloc(8L * 1024 * 4096 * 2);
  bf16* ln_h = (bf16*)alloc(4096L * 1024 * 2);  // ln1 then reused for ln2
  bf16* ln_l = (bf16*)alloc(4096L * 1024 * 2);
  bf16* attn_h = (bf16*)alloc(4096L * 1024 * 2);
  bf16* attn_l = (bf16*)alloc(4096L * 1024 * 2);
  int*   perm  = (int*)alloc(8L * 4096 * 4);
  float* gatew = (float*)alloc(8L * 4096 * 4);
  int2*  topi  = (int2*)alloc(4096L * 8);
  float2* topg = (float2*)alloc(4096L * 8);
  float* pbuf  = (float*)alloc(4096L * 8 * 4);
  char*  ctrl  = alloc(256);                 // ecnt[8] | eoff[8]
  int*   ecnt  = (int*)ctrl;
  int*   eoff  = (int*)(ctrl + 64);
  // big overlay region: [qkv fp32 48MB | rope hi/lo bufs 48MB] then h (73MB)
  char* big = alloc(100663296);
  float* qkvf = (float*)big;                           // 4096*3072*4
  bf16* qh = (bf16*)(big + 50331648);
  bf16* ql = qh + 4194304;
  bf16* kh = ql + 4194304;
  bf16* kl = kh + 4194304;
  bf16* vh = kl + 4194304;
  bf16* vl = vh + 4194304;
  bf16* hbuf = (bf16*)big;                             // 9216*4096*2, after attn

  dim3 blk(256);

  // 1) weight transpose + cast
  k_transpose_cast<<<dim3(3072 / 32, 1024 / 32, 1), blk, 0, stream>>>(wqkv, wqkvT_h, wqkvT_l, 1024, 3072);
  k_transpose_cast<<<dim3(1024 / 32, 1024 / 32, 1), blk, 0, stream>>>(wproj, wprojT_h, wprojT_l, 1024, 1024);
  k_transpose_cast<<<dim3(4096 / 32, 1024 / 32, 8), blk, 0, stream>>>(w1, w1T, nullptr, 1024, 4096);
  k_transpose_cast<<<dim3(1024 / 32, 4096 / 32, 8), blk, 0, stream>>>(w2, w2T, nullptr, 4096, 1024);
  hipMemsetAsync(ctrl, 0, 256, stream);

  // 2) attention path (split precision)
  k_layernorm<<<4096, blk, 0, stream>>>(x, ln1g, ln1b, ln_h, ln_l);
  k_gemm_qkv<<<dim3(24, 32), blk, 0, stream>>>(ln_h, ln_l, wqkvT_h, wqkvT_l, qkvf);
  k_rope<<<4096, blk, 0, stream>>>(qkvf, qh, ql, kh, kl, vh, vl);
  k_flash<<<dim3(16, 64), blk, 0, stream>>>(qh, ql, kh, kl, vh, vl, attn_h, attn_l);
  k_gemm_proj<<<dim3(8, 32), blk, 0, stream>>>(attn_h, attn_l, wprojT_h, wprojT_l, bproj, x, out);

  // 3) MoE
  k_layernorm<<<4096, blk, 0, stream>>>(out, ln2g, ln2b, ln_h, nullptr);
  k_router<<<4096, blk, 0, stream>>>(out, ln2g, ln2b, wrout, topi, topg, pbuf);
  k_scatter<<<16, blk, 0, stream>>>(topi, topg, ecnt, perm, gatew);
  k_finalize<<<1, blk, 0, stream>>>(ecnt, pbuf, eoff, out + 4194304);
  k_gemm_ffn1<<<dim3(32, 256), blk, 0, stream>>>(ln_h, w1T, b1, ecnt, eoff, perm, hbuf);
  k_gemm_ffn2<<<dim3(8, 256), blk, 0, stream>>>(hbuf, w2T, b2, ecnt, eoff, perm, gatew, out);
}